// Round 1
// 127.666 us; speedup vs baseline: 1.0466x; 1.0466x over previous
//
#include <hip/hip_runtime.h>
#include <hip/hip_fp16.h>

// Problem constants (fixed by the reference)
constexpr int L = 64;     // sites
constexpr int P = 4;      // physical dim
constexpr int D = 128;    // bond dim
constexpr int B = 2048;   // batch
constexpr int EPW = 16;   // batch elements per WG (one mfma M-tile)
constexpr int NG = B / EPW;   // 128 batch groups -> 256 WGs (fwd+bwd)

using v8h = __attribute__((ext_vector_type(8))) _Float16;  // mfma A/B frag
using v4h = __attribute__((ext_vector_type(4))) _Float16;
using v4f = __attribute__((ext_vector_type(4))) float;     // mfma C/D frag

// ---- workspace layout (bytes); TOTAL 10 MB ------------------------------
constexpr size_t UT_OFF  = 0;               // u_t fp32 [d][b]   1 MB
constexpr size_t WT_OFF  = 1048576;         // w_t fp32 [d][b]   1 MB
constexpr size_t MTF_OFF = 2097152;         // sites 0..31  fp16 [mat][c][d] 4 MB
constexpr size_t MTB_OFF = 6291456;         // sites 32..63 fp16 [mat][d][c] 4 MB

// ---- chain-kernel LDS map (bytes) ---------------------------------------
constexpr int VLDS0 = 131072;
constexpr int VLDS1 = 131072 + 4096;
constexpr int PLDS  = 131072 + 8192;
constexpr int SMEM_BYTES = PLDS + L * EPW * 4;  // 143360 -> 1 WG/CU, 8 waves

// s_waitcnt immediates (gfx9: vmcnt[3:0] | exp<<4 | lgkm<<8 | vmcnt[5:4]<<14)
#define WAIT_VM8   0xF78   // vmcnt(8) — drain all but the newest 8 loads
#define WAIT_VM0   0xF70   // vmcnt(0)
#define WAIT_LGKM0 0xC07F  // lgkmcnt(0) only; vmcnt untouched

__device__ __forceinline__ void gl2lds16(const void* g, void* l) {
  __builtin_amdgcn_global_load_lds(
      (const __attribute__((address_space(1))) void*)g,
      (__attribute__((address_space(3))) void*)l, 16, 0, 0);
}

// ---------------------------------------------------------------------------
// Convert fp32 [site][p][d][c]:
//   sites 32..63 -> mtb, row-major fp16 [d][c]  (bwd B-frags) — straight cast
//   sites  0..31 -> mtf, transposed fp16 [c][d] (fwd B-frags) — REGISTER
//     transpose, no LDS (R7's LDS path had 16-way bank conflicts).
//   R8: split each matrix across 2 blocks (512 blocks total) — 256 blocks
//   was 1 small block/CU (4 waves, 12.5% occupancy), latency-bound.
// ---------------------------------------------------------------------------
__global__ void convert_dual(const float* __restrict__ src,
                             _Float16* __restrict__ mtf,
                             _Float16* __restrict__ mtb) {
  const int mat  = blockIdx.x >> 1;   // site*P + p
  const int half = blockIdx.x & 1;
  const int site = mat >> 2;
  const int t = threadIdx.x;
  if (site >= 32) {                   // bwd half: straight cast, keep [d][c]
    const float4* sb = (const float4*)(src + (size_t)mat * 16384);
    _Float16* bb = mtb + (size_t)(mat - 128) * 16384;
#pragma unroll
    for (int it = 0; it < 8; ++it) {
      int idx = t + (half * 8 + it) * 256;   // 4096 float4 per matrix
      float4 f = sb[idx];
      v4h h4 = {(_Float16)f.x, (_Float16)f.y, (_Float16)f.z, (_Float16)f.w};
      *(v4h*)(bb + idx * 4) = h4;
    }
    return;
  }
  // fwd half: register transpose; this block does c-half = `half`
  const float* sb = src + (size_t)mat * 16384;
  _Float16* fb = mtf + (size_t)mat * 16384;
  const int cl = t & 63;              // c within 64-lane run (coalesced dim)
  const int dg = t >> 6;              // d8 group 0..3
  const int c = half * 64 + cl;
#pragma unroll
  for (int dh = 0; dh < 4; ++dh) {    // d8 = dh*4 + dg
    const int d8 = dh * 4 + dg;
    v8h v;
#pragma unroll
    for (int j = 0; j < 8; ++j) v[j] = (_Float16)sb[(d8 * 8 + j) * D + c];
    *(v8h*)(fb + c * D + d8 * 8) = v;
  }
}

// ---------------------------------------------------------------------------
// Half-chain kernel: 256 WGs x 8 waves x 16 elements; even blockIdx = fwd
// (sites 0..31 ascending, u = l^T prod M), odd = bwd (sites 63..32
// descending, w = prod M r; same GEMM via mtb).
//
// R8 sync restructure (counted-vmcnt pipeline, T3/T4):
//  - Chunk buffers are WAVE-PRIVATE -> the per-site __syncthreads (which
//    compiles to s_waitcnt vmcnt(0) and drained the just-issued next-site
//    prefetch 32x per chain) is replaced by lgkmcnt(0) + raw s_barrier.
//    The only cross-wave state is the 4 KB v-exchange ping-pong (LDS-pipe,
//    lgkm-tracked). vmcnt invariant: exactly 8 loads (next-site buf0
//    prefetch) stay in flight ACROSS every barrier -> L2 stream never
//    drains mid-chain.
//  - buf0 consumption gate: stage(buf1) first (16 in flight), then
//    vmcnt(8) retires exactly the 8 oldest = buf0's chunk.
//  - buf1 consumption gate: stage(next buf0) (16 in flight), vmcnt(8)
//    retires the 8 oldest = buf1's chunk.  Last site: vmcnt(0).
//  - WAR fences (ds_read vs DMA are UNORDERED in HW — the R4-R6
//    corruption): each wave drains its OWN lgkmcnt(0) before any DMA
//    overwrite of a buffer it just ds_read, and before the barrier (which
//    also publishes the v-exchange). sched_barrier(0) pins compiler order
//    around every waitcnt/barrier.
// Frag layouts: A[m=lane&15][k=q4*8+j], B^T[n=lane&15][k=q4*8+j],
// C[row=q4*4+r][col=lane&15]. Chunk LDS: [p][c16][kseg8] 16B units,
// kseg slot ^= (c&7); staging bakes inverse swizzle into global address.
// ---------------------------------------------------------------------------
__global__ __launch_bounds__(512, 1) void mps_half_chain(
    const int* __restrict__ onstate, const _Float16* __restrict__ mtf,
    const _Float16* __restrict__ mtb, const float* __restrict__ left_vec,
    const float* __restrict__ right_vec, float* __restrict__ ut,
    float* __restrict__ wt) {
  extern __shared__ char smem[];
  const int tid = threadIdx.x;
  const int wave = tid >> 6, lane = tid & 63;
  const int me = lane & 15, q4 = lane >> 4;
  const bool fwd = !(blockIdx.x & 1);
  const int b0 = (blockIdx.x >> 1) * EPW;
  const _Float16* mbase = fwd ? mtf : mtb;   // my half's 128 matrices
  const float* ivec = fwd ? left_vec : right_vec;
  float* ovec = fwd ? ut : wt;

  // ---- stage onstate -> plds[site][e] (global site index)
  int* plds = (int*)(smem + PLDS);
#pragma unroll
  for (int j = 0; j < 2; ++j) {
    int idx = tid + j * 512;
    int e = idx >> 6, i = idx & 63;
    plds[i * EPW + e] = onstate[(b0 + e) * L + i];
  }
  // ---- init v = ivec for every element (swizzled fp16)
  if (tid < 256) {
    int e = tid >> 4, seg = tid & 15;
    _Float16* vp = (_Float16*)(smem + VLDS0) + e * 128 + (seg ^ (e & 7)) * 8;
#pragma unroll
    for (int j = 0; j < 8; ++j) vp[j] = (_Float16)ivec[seg * 8 + j];
  }

  char* wbuf = smem + wave * 16384;   // my private 2 x 8 KB chunk buffers

  // per-lane, site-invariant staging source offsets (inverse swizzle baked)
  int soff[8];
#pragma unroll
  for (int i = 0; i < 8; ++i) {
    int u = i * 64 + lane;
    int p = u >> 7, r = u & 127, cl = r >> 3, slot = r & 7;
    soff[i] = p * 32768 + (wave * 16 + cl) * 256 + (slot ^ (cl & 7)) * 16;
  }
  // stage chunk (local site ls in 0..31, k-half h) into buffer z
  auto stage = [&](int ls, int h, int z) {
    const char* gb = (const char*)mbase + (size_t)ls * 131072 + h * 128;
    char* lb = wbuf + z * 8192;
#pragma unroll
    for (int i = 0; i < 8; ++i) gl2lds16(gb + soff[i], lb + i * 1024);
  };
  // consume k-half h of the chunk in buffer z into acc (masked by pm)
  auto consume = [&](int h, int z, int pm, const char* vb, v4f& acc) {
    const int s0 = h * 8 + q4, s1 = h * 8 + 4 + q4;
    v8h a0 = *(const v8h*)(vb + me * 256 + (s0 ^ (me & 7)) * 16);
    v8h a1 = *(const v8h*)(vb + me * 256 + (s1 ^ (me & 7)) * 16);
    const char* cb = wbuf + z * 8192;
#pragma unroll
    for (int p = 0; p < P; ++p) {
      const bool isp = (pm == p);
      v8h zf = {};
      v8h am0 = isp ? a0 : zf;
      v8h am1 = isp ? a1 : zf;
      const char* pb = cb + p * 2048 + me * 128;
      v8h bf0 = *(const v8h*)(pb + ((q4) ^ (me & 7)) * 16);
      v8h bf1 = *(const v8h*)(pb + ((4 + q4) ^ (me & 7)) * 16);
      acc = __builtin_amdgcn_mfma_f32_16x16x32_f16(am0, bf0, acc, 0, 0, 0);
      acc = __builtin_amdgcn_mfma_f32_16x16x32_f16(am1, bf1, acc, 0, 0, 0);
    }
  };

  __syncthreads();                    // plds + v-init visible (full drain, 1x)
  stage(fwd ? 0 : 31, 0, 0);          // prologue: chunk g=0 -> buf0 (8 vm)

  const int c0 = wave * 16 + me;      // my output column
  v4f accL = {0.f, 0.f, 0.f, 0.f};
  for (int site = 0; site < 32; ++site) {
    const int site_g = fwd ? site : 63 - site;   // global site (plds index)
    const int ls     = fwd ? site : 31 - site;   // local site in my half
    const int pm = plds[site_g * EPW + me];
    const char* vb = smem + ((site & 1) ? VLDS1 : VLDS0);
    v4f acc = {0.f, 0.f, 0.f, 0.f};

    // ---- h = 0: issue (ls, h=1) -> buf1; gate buf0 with counted vmcnt
    stage(ls, 1, 1);                          // in flight: 8 buf0 + 8 buf1
    __builtin_amdgcn_s_waitcnt(WAIT_VM8);     // oldest 8 (buf0) complete
    __builtin_amdgcn_sched_barrier(0);
    consume(0, 0, pm, vb, acc);

    // ---- h = 1
    if (site < 31) {
      const int lsn = fwd ? site + 1 : 30 - site;
      // hazard fence: drain my LDS-pipe reads of buf0 before DMA-writing it
      __builtin_amdgcn_sched_barrier(0);
      __builtin_amdgcn_s_waitcnt(WAIT_LGKM0);
      __builtin_amdgcn_sched_barrier(0);
      stage(lsn, 0, 0);                       // prefetch next site -> buf0
      __builtin_amdgcn_s_waitcnt(WAIT_VM8);   // oldest 8 (buf1) complete
      __builtin_amdgcn_sched_barrier(0);
      consume(1, 1, pm, vb, acc);
      // v-exchange: write v_new fp16 (C-layout rows) to the other buffer
      _Float16* vn = (_Float16*)(smem + ((site & 1) ? VLDS0 : VLDS1));
#pragma unroll
      for (int r = 0; r < 4; ++r) {
        int e = q4 * 4 + r;
        vn[e * 128 + ((c0 >> 3) ^ (e & 7)) * 8 + (c0 & 7)] = (_Float16)acc[r];
      }
      // site boundary: publish v-exchange + retire my ds_reads, but keep
      // the 8 buf0-prefetch loads in flight ACROSS the barrier.
      __builtin_amdgcn_sched_barrier(0);
      __builtin_amdgcn_s_waitcnt(WAIT_LGKM0);
      __builtin_amdgcn_s_barrier();
      __builtin_amdgcn_sched_barrier(0);
    } else {
      __builtin_amdgcn_s_waitcnt(WAIT_VM0);   // last chunk: full drain
      __builtin_amdgcn_sched_barrier(0);
      consume(1, 1, pm, vb, acc);
      accL = acc;
    }
  }
  // ---- epilogue: store half-chain vector transposed [d][b] (fp32)
#pragma unroll
  for (int r = 0; r < 4; ++r) ovec[c0 * B + b0 + q4 * 4 + r] = accL[r];
}

// ---------------------------------------------------------------------------
// Combine: amp[b] = sum_d u[d][b] * w[d][b]  (coalesced along b)
// R8: 32 blocks (was 8) — 4 waves split d-range, LDS cross-wave reduce.
// ---------------------------------------------------------------------------
__global__ void combine_uw(const float* __restrict__ ut,
                           const float* __restrict__ wt,
                           float* __restrict__ out) {
  __shared__ float red[256];
  const int t = threadIdx.x;
  const int b = blockIdx.x * 64 + (t & 63);
  const int w = t >> 6;
  float s = 0.f;
#pragma unroll
  for (int i = 0; i < 32; ++i) {
    const int d = w * 32 + i;
    s += ut[d * B + b] * wt[d * B + b];
  }
  red[t] = s;
  __syncthreads();
  if (t < 64) out[b] = red[t] + red[t + 64] + red[t + 128] + red[t + 192];
}

// ---------------------------------------------------------------------------
extern "C" void kernel_launch(void* const* d_in, const int* in_sizes, int n_in,
                              void* d_out, int out_size, void* d_ws,
                              size_t ws_size, hipStream_t stream) {
  const int*   onstate      = (const int*)d_in[0];
  const float* site_tensors = (const float*)d_in[1];
  const float* left_vec     = (const float*)d_in[2];
  const float* right_vec    = (const float*)d_in[3];
  float*       out          = (float*)d_out;
  char*        ws           = (char*)d_ws;   // needs 10 MB
  float*       ut           = (float*)(ws + UT_OFF);
  float*       wt           = (float*)(ws + WT_OFF);
  _Float16*    mtf          = (_Float16*)(ws + MTF_OFF);
  _Float16*    mtb          = (_Float16*)(ws + MTB_OFF);

  hipFuncSetAttribute((const void*)mps_half_chain,
                      hipFuncAttributeMaxDynamicSharedMemorySize, SMEM_BYTES);

  convert_dual<<<L * P * 2, 256, 0, stream>>>(site_tensors, mtf, mtb);
  mps_half_chain<<<2 * NG, 512, SMEM_BYTES, stream>>>(
      onstate, mtf, mtb, left_vec, right_vec, ut, wt);
  combine_uw<<<B / 64, 256, 0, stream>>>(ut, wt, out);
}

// Round 2
// 115.903 us; speedup vs baseline: 1.1528x; 1.1015x over previous
//
#include <hip/hip_runtime.h>
#include <hip/hip_fp16.h>

// Problem constants (fixed by the reference)
constexpr int L = 64;     // sites
constexpr int P = 4;      // physical dim
constexpr int D = 128;    // bond dim
constexpr int B = 2048;   // batch
constexpr int EPW = 16;   // batch elements per WG (one mfma M-tile)
constexpr int NG = B / EPW;   // 128 batch groups -> 256 WGs (fwd+bwd)

using v8h = __attribute__((ext_vector_type(8))) _Float16;  // mfma A/B frag
using v4f = __attribute__((ext_vector_type(4))) float;     // mfma C/D frag

// ---- workspace layout (bytes); TOTAL 10 MB ------------------------------
constexpr size_t UT_OFF  = 0;               // u_t fp32 [d][b]   1 MB
constexpr size_t WT_OFF  = 1048576;         // w_t fp32 [d][b]   1 MB
constexpr size_t MTF_OFF = 2097152;         // sites 0..31  fp16 frag-layout 4 MB
constexpr size_t MTB_OFF = 6291456;         // sites 32..63 fp16 frag-layout 4 MB
// frag layout (fp16 units): [site][p][kh][w][q4][me][j]
//   site stride 65536, p 16384, kh 4096, w 512, q4 128, me 8, j 1
// frag (p,kh) for lane (w,q4,me) = B^T[col=w*16+me][k=(kh*4+q4)*8 + j]
// -> one global_load_dwordx4 per frag, 64 lanes = 1 KB contiguous.

// s_waitcnt immediates (gfx9: vmcnt[3:0] | exp<<4 | lgkm<<8 | vmcnt[5:4]<<14)
#define WAIT_LGKM0 0xC07F  // lgkmcnt(0) only; vmcnt untouched

// ---------------------------------------------------------------------------
// Convert fp32 src[site][p][d][c] (row-major 128x128) into frag layout.
//   fwd (sites 0..31):  B^T[col][k] = M[k][col]  -> column gather (register
//     transpose, 64B-coalesced across me-lanes)
//   bwd (sites 32..63): B^T[col][k] = M[col][k]  -> row slice, fully
//     coalesced float4 reads AND v8h writes.
// grid 512 x 256: block = (mat, kh-half); 4 waves x 4 (kh,w) combos.
// ---------------------------------------------------------------------------
__global__ void convert_dual(const float* __restrict__ src,
                             _Float16* __restrict__ mtf,
                             _Float16* __restrict__ mtb) {
  const int mat  = blockIdx.x >> 1;   // site*P + p
  const int half = blockIdx.x & 1;
  const int site = mat >> 2, p = mat & 3;
  const int wave = threadIdx.x >> 6, lane = threadIdx.x & 63;
  const int me = lane & 15, q4 = lane >> 4;
  const float* sb = src + (size_t)mat * 16384;

  if (site >= 32) {   // bwd: row slices, coalesced both sides
    _Float16* ob = mtb + (size_t)(site - 32) * 65536 + p * 16384;
#pragma unroll
    for (int i = 0; i < 4; ++i) {
      const int kh = half * 2 + (i >> 1);
      const int w  = (i & 1) * 4 + wave;
      const float4* rp =
          (const float4*)(sb + (w * 16 + me) * 128 + (kh * 4 + q4) * 8);
      float4 f0 = rp[0], f1 = rp[1];
      v8h v = {(_Float16)f0.x, (_Float16)f0.y, (_Float16)f0.z, (_Float16)f0.w,
               (_Float16)f1.x, (_Float16)f1.y, (_Float16)f1.z, (_Float16)f1.w};
      *(v8h*)(ob + kh * 4096 + w * 512 + q4 * 128 + me * 8) = v;
    }
    return;
  }
  // fwd: column gather (register transpose)
  _Float16* ob = mtf + (size_t)site * 65536 + p * 16384;
#pragma unroll
  for (int i = 0; i < 4; ++i) {
    const int kh = half * 2 + (i >> 1);
    const int w  = (i & 1) * 4 + wave;
    v8h v;
#pragma unroll
    for (int j = 0; j < 8; ++j)
      v[j] = (_Float16)sb[((kh * 4 + q4) * 8 + j) * 128 + w * 16 + me];
    *(v8h*)(ob + kh * 4096 + w * 512 + q4 * 128 + me * 8) = v;
  }
}

// ---------------------------------------------------------------------------
// Half-chain kernel, R9: register-resident B-frags, NO matrix LDS.
//   256 WGs x 8 waves x 16 elements; even blockIdx = fwd (u = l^T prod M),
//   odd = bwd (w = prod M r).  Per site per wave: 16 global_load_dwordx4
//   directly into a v8h bank (frag layout above), 16 masked MFMAs, v
//   exchanged through a 4 KB LDS ping-pong.  Banks double-buffered in
//   registers (static names bank0/bank1 -> no scratch); prefetch of site
//   s+1 issues before site s's MFMAs, compiler gates with vmcnt(16), and
//   raw s_barrier + lgkm-only fence keeps those 16 loads in flight across
//   every site boundary.
// Frag layouts: A[m=lane&15][k=q4*8+j], B^T[n=me][k], C[row=q4*4+r][col=me].
// consume(h) pairs A kseg h*8+q4 with bank[p*4+2h], kseg h*8+4+q4 with
// bank[p*4+2h+1]  (bank i=(p*4+kh) holds kseg kh*4+q4).
// v LDS layout (per proven R7 code): v[e*128 + (seg^(e&7))*8 + j].
// ---------------------------------------------------------------------------
__global__ __launch_bounds__(512, 2) void mps_half_chain(
    const int* __restrict__ onstate, const _Float16* __restrict__ mtf,
    const _Float16* __restrict__ mtb, const float* __restrict__ left_vec,
    const float* __restrict__ right_vec, float* __restrict__ ut,
    float* __restrict__ wt) {
  __shared__ _Float16 vlds[2][2048];   // 2 x 4 KB v ping-pong
  __shared__ int plds[L * EPW];        // 4 KB occupations
  const int tid = threadIdx.x;
  const int wave = tid >> 6, lane = tid & 63;
  const int me = lane & 15, q4 = lane >> 4;
  const bool fwd = !(blockIdx.x & 1);
  const int b0 = (blockIdx.x >> 1) * EPW;
  const _Float16* mbase = fwd ? mtf : mtb;
  const float* ivec = fwd ? left_vec : right_vec;
  float* ovec = fwd ? ut : wt;

  // ---- stage onstate -> plds[site][e] (global site index)
#pragma unroll
  for (int j = 0; j < 2; ++j) {
    int idx = tid + j * 512;
    int e = idx >> 6, i = idx & 63;
    plds[i * EPW + e] = onstate[(b0 + e) * L + i];
  }
  // ---- init v = ivec for every element (swizzled fp16)
  if (tid < 256) {
    int e = tid >> 4, seg = tid & 15;
    _Float16* vp = &vlds[0][0] + e * 128 + (seg ^ (e & 7)) * 8;
#pragma unroll
    for (int j = 0; j < 8; ++j) vp[j] = (_Float16)ivec[seg * 8 + j];
  }

  // per-lane site-invariant global base for my 16 frags
  const _Float16* gbase = mbase + wave * 512 + lane * 8;
  auto stageR = [&](v8h (&bank)[16], int ls) {
    const v8h* gp = (const v8h*)(gbase + (size_t)ls * 65536);
#pragma unroll
    for (int i = 0; i < 16; ++i) bank[i] = gp[i * 512];  // stride 8 KB
  };
  // consume both k-halves of a bank into acc (masked by pm)
  auto consumeSite = [&](v8h (&bank)[16], int pm, const _Float16* vb,
                         v4f& acc) {
#pragma unroll
    for (int h = 0; h < 2; ++h) {
      const int s0 = h * 8 + q4, s1 = s0 + 4;
      v8h a0 = *(const v8h*)(vb + me * 128 + (s0 ^ (me & 7)) * 8);
      v8h a1 = *(const v8h*)(vb + me * 128 + (s1 ^ (me & 7)) * 8);
#pragma unroll
      for (int p = 0; p < P; ++p) {
        const bool isp = (pm == p);
        v8h zf = {};
        v8h am0 = isp ? a0 : zf;
        v8h am1 = isp ? a1 : zf;
        acc = __builtin_amdgcn_mfma_f32_16x16x32_f16(am0, bank[p * 4 + 2 * h],
                                                     acc, 0, 0, 0);
        acc = __builtin_amdgcn_mfma_f32_16x16x32_f16(
            am1, bank[p * 4 + 2 * h + 1], acc, 0, 0, 0);
      }
    }
  };
  const int c0 = wave * 16 + me;      // my output column
  auto writeV = [&](_Float16* vn, const v4f& acc) {
#pragma unroll
    for (int r = 0; r < 4; ++r) {
      int e = q4 * 4 + r;
      vn[e * 128 + ((c0 >> 3) ^ (e & 7)) * 8 + (c0 & 7)] = (_Float16)acc[r];
    }
  };

  __syncthreads();                    // plds + v-init visible (full drain, 1x)

  v8h bank0[16], bank1[16];
  stageR(bank0, fwd ? 0 : 31);        // prologue: site 0 frags in flight

  v4f accL = {0.f, 0.f, 0.f, 0.f};
  for (int s2 = 0; s2 < 16; ++s2) {
    const int se = 2 * s2, so = se + 1;
    // ---- even site: consume bank0, prefetch odd site -> bank1
    {
      const int sg = fwd ? se : 63 - se;
      const int pm = plds[sg * EPW + me];
      stageR(bank1, fwd ? so : 31 - so);
      v4f acc = {0.f, 0.f, 0.f, 0.f};
      consumeSite(bank0, pm, &vlds[0][0], acc);
      writeV(&vlds[1][0], acc);
      // publish v-exchange; bank1's 16 loads stay in flight across barrier
      __builtin_amdgcn_sched_barrier(0);
      __builtin_amdgcn_s_waitcnt(WAIT_LGKM0);
      __builtin_amdgcn_s_barrier();
      __builtin_amdgcn_sched_barrier(0);
    }
    // ---- odd site: consume bank1, prefetch next even site -> bank0
    {
      const int sg = fwd ? so : 63 - so;
      const int pm = plds[sg * EPW + me];
      const int sn = (so + 1) & 31;              // wrap at 31: harmless refetch
      stageR(bank0, fwd ? sn : 31 - sn);
      v4f acc = {0.f, 0.f, 0.f, 0.f};
      consumeSite(bank1, pm, &vlds[1][0], acc);
      if (so < 31) {
        writeV(&vlds[0][0], acc);
        __builtin_amdgcn_sched_barrier(0);
        __builtin_amdgcn_s_waitcnt(WAIT_LGKM0);
        __builtin_amdgcn_s_barrier();
        __builtin_amdgcn_sched_barrier(0);
      } else {
        accL = acc;
      }
    }
  }
  // ---- epilogue: store half-chain vector transposed [d][b] (fp32)
#pragma unroll
  for (int r = 0; r < 4; ++r) ovec[c0 * B + b0 + q4 * 4 + r] = accL[r];
}

// ---------------------------------------------------------------------------
// Combine: amp[b] = sum_d u[d][b] * w[d][b]  (coalesced along b)
// 32 blocks — 4 waves split d-range, LDS cross-wave reduce.
// ---------------------------------------------------------------------------
__global__ void combine_uw(const float* __restrict__ ut,
                           const float* __restrict__ wt,
                           float* __restrict__ out) {
  __shared__ float red[256];
  const int t = threadIdx.x;
  const int b = blockIdx.x * 64 + (t & 63);
  const int w = t >> 6;
  float s = 0.f;
#pragma unroll
  for (int i = 0; i < 32; ++i) {
    const int d = w * 32 + i;
    s += ut[d * B + b] * wt[d * B + b];
  }
  red[t] = s;
  __syncthreads();
  if (t < 64) out[b] = red[t] + red[t + 64] + red[t + 128] + red[t + 192];
}

// ---------------------------------------------------------------------------
extern "C" void kernel_launch(void* const* d_in, const int* in_sizes, int n_in,
                              void* d_out, int out_size, void* d_ws,
                              size_t ws_size, hipStream_t stream) {
  const int*   onstate      = (const int*)d_in[0];
  const float* site_tensors = (const float*)d_in[1];
  const float* left_vec     = (const float*)d_in[2];
  const float* right_vec    = (const float*)d_in[3];
  float*       out          = (float*)d_out;
  char*        ws           = (char*)d_ws;   // needs 10 MB
  float*       ut           = (float*)(ws + UT_OFF);
  float*       wt           = (float*)(ws + WT_OFF);
  _Float16*    mtf          = (_Float16*)(ws + MTF_OFF);
  _Float16*    mtb          = (_Float16*)(ws + MTB_OFF);

  convert_dual<<<L * P * 2, 256, 0, stream>>>(site_tensors, mtf, mtb);
  mps_half_chain<<<2 * NG, 512, 0, stream>>>(
      onstate, mtf, mtb, left_vec, right_vec, ut, wt);
  combine_uw<<<B / 64, 256, 0, stream>>>(ut, wt, out);
}